// Round 5
// baseline (540.189 us; speedup 1.0000x reference)
//
#include <hip/hip_runtime.h>
#include <hip/hip_bf16.h>

#define NN 50000
#define NE 800000
#define DD 128

typedef unsigned int u32;
typedef __attribute__((ext_vector_type(8))) short short8;   // 8 bf16 = 4 VGPRs
typedef __attribute__((ext_vector_type(4))) float f32x4;
typedef __attribute__((ext_vector_type(4))) u32 u32x4;

__device__ __forceinline__ u32 f2bf2(float a, float b){
  union { __hip_bfloat162 h; u32 u; } cv;
  cv.h = __float22bfloat162_rn(make_float2(a, b));   // v_cvt_pk_bf16_f32 on gfx950
  return cv.u;
}
__device__ __forceinline__ float blo(u32 v){ return __uint_as_float(v << 16); }
__device__ __forceinline__ float bhi(u32 v){ return __uint_as_float(v & 0xffff0000u); }

// ---------------- weight prep: fp32 W -> frag-ordered bf16 (once per launch) ------
struct PrepArgs { const float* W[6]; u32* out; };
__global__ __launch_bounds__(256) void k_prep(PrepArgs pa){
  int tid = blockIdx.x*256 + threadIdx.x;        // 6 mats * 32 frags * 64 lanes
  int mat = tid >> 11, rem = tid & 2047;
  int frag = rem >> 6, lane = rem & 63;
  int ct = frag >> 2, ks = frag & 3, rr = lane & 15, quad = lane >> 4;
  const float* p = pa.W[mat] + (ct*16 + rr)*128 + ks*32 + quad*8;
  float4 f0 = *(const float4*)p;
  float4 f1 = *(const float4*)(p + 4);
  u32x4 q;
  q.x = f2bf2(f0.x, f0.y); q.y = f2bf2(f0.z, f0.w);
  q.z = f2bf2(f1.x, f1.y); q.w = f2bf2(f1.z, f1.w);
  *(u32x4*)(pa.out + (size_t)tid*4) = q;
}

// ---------------- CSR build ----------------
__global__ void k_hist(const int* __restrict__ dst, int* __restrict__ cnt){
  int i = blockIdx.x*256 + threadIdx.x;
  if (i < NE) atomicAdd(&cnt[dst[i]], 1);
}

// hierarchical scan: 49 blocks x 1024 local scan -> 1-wave scan of totals -> add
__global__ __launch_bounds__(1024) void k_scan1(const int* __restrict__ cnt,
                                                int* __restrict__ rs,
                                                int* __restrict__ btot){
  __shared__ int wsum[16];
  const int t = threadIdx.x, lane = t & 63, wid = t >> 6;
  int i = blockIdx.x*1024 + t;
  int v = (i < NN) ? cnt[i] : 0;
  int incl = v;
  #pragma unroll
  for (int off = 1; off < 64; off <<= 1){
    int u = __shfl_up(incl, off, 64);
    if (lane >= off) incl += u;
  }
  if (lane == 63) wsum[wid] = incl;
  __syncthreads();
  if (wid == 0){
    int w = (lane < 16) ? wsum[lane] : 0;
    #pragma unroll
    for (int off = 1; off < 16; off <<= 1){
      int u = __shfl_up(w, off, 64);
      if (lane >= off) w += u;
    }
    if (lane < 16) wsum[lane] = w;
  }
  __syncthreads();
  int base = (wid > 0) ? wsum[wid-1] : 0;
  if (i < NN) rs[i] = base + incl - v;
  if (t == 0) btot[blockIdx.x] = wsum[15];
}

__global__ void k_scan2(const int* __restrict__ btot, int* __restrict__ bbase,
                        int* __restrict__ rs){
  int lane = threadIdx.x;           // 64 threads, 1 block
  int v = (lane < 49) ? btot[lane] : 0;
  int incl = v;
  #pragma unroll
  for (int off = 1; off < 64; off <<= 1){
    int u = __shfl_up(incl, off, 64);
    if (lane >= off) incl += u;
  }
  if (lane < 49) bbase[lane] = incl - v;
  if (lane == 48) rs[NN] = incl;    // grand total = NE
}

__global__ __launch_bounds__(1024) void k_scan3(int* __restrict__ rs,
                                                const int* __restrict__ bbase,
                                                int* __restrict__ cursor){
  int i = blockIdx.x*1024 + threadIdx.x;
  if (i < NN){
    int r = rs[i] + bbase[blockIdx.x];
    rs[i] = r; cursor[i] = r;
  }
}

__global__ void k_scatter(const int* __restrict__ src, const int* __restrict__ dst,
                          int* __restrict__ cursor, int* __restrict__ esrc){
  int i = blockIdx.x*256 + threadIdx.x;
  if (i < NE){
    int d = dst[i];
    int p = atomicAdd(&cursor[d], 1);
    esrc[p] = src[i];
  }
}

// ------------- fused pre-transform + bf16-MFMA GEMM, software-pipelined -----------
// W (frag-packed bf16) in 32 KB LDS per block; each wave loads its own 16 A-rows
// straight into MFMA B-frag registers; prefetch next group's A during MFMA.
struct GemmArgs {
  const float* A[3];
  const float* Bias[3];
  const u32* Wf;          // frag-packed weights for this layer (3 mats)
  u32* H;                 // manifold m at H + m*NN*64
  const float* curv;
  int astride;
};

__global__ __launch_bounds__(256,3) void k_gemm(GemmArgs ga){
  const int m = blockIdx.y;
  const float* __restrict__ A    = ga.A[m];
  const float* __restrict__ Bias = ga.Bias[m];
  u32* __restrict__ H = ga.H + (size_t)m*NN*64;
  const int astride = ga.astride;
  const int t = threadIdx.x;
  const int lane = t & 63;
  const int rr = lane & 15, quad = lane >> 4;

  __shared__ u32 Wlds[8192];        // 32 frags x 64 lanes x 16 B, conflict-free b128
  {
    const u32x4* wsrc = (const u32x4*)(ga.Wf + (size_t)m*8192);
    #pragma unroll
    for (int it = 0; it < 8; ++it){
      int idx = it*256 + t;
      *(u32x4*)&Wlds[idx*4] = wsrc[idx];
    }
  }
  __syncthreads();                  // the only barrier in the kernel

  float sc = 1.f;
  if (m == 1) sc = sqrtf(*ga.curv);

  // bias frags hoisted out of the loop (constant per kernel)
  float4 bv[8];
  #pragma unroll
  for (int ct = 0; ct < 8; ++ct) bv[ct] = *(const float4*)(Bias + ct*16 + quad*4);

  auto load8 = [&](float4* c, int g){
    const float* ap = A + (size_t)(g*16 + rr)*astride + quad*8;
    #pragma unroll
    for (int ks = 0; ks < 4; ++ks){
      c[2*ks]   = *(const float4*)(ap + ks*32);
      c[2*ks+1] = *(const float4*)(ap + ks*32 + 4);
    }
  };

  const int step = gridDim.x * 4;
  int g = blockIdx.x*4 + (t >> 6);
  float4 c[8], cn[8];
  if (g < 3125) load8(c, g);

  for (; g < 3125; g += step){
    const int g2 = g + step;
    if (g2 < 3125) load8(cn, g2);          // prefetch overlaps everything below

    // ---- row-norm pre-transform (register shuffles, no LDS) ----
    if (m != 0){
      float p = 0.f;
      #pragma unroll
      for (int i = 0; i < 8; ++i)
        p += c[i].x*c[i].x + c[i].y*c[i].y + c[i].z*c[i].z + c[i].w*c[i].w;
      p += __shfl_xor(p, 16, 64);
      p += __shfl_xor(p, 32, 64);
      float nrm = sqrtf(p);
      float sca;
      if (m == 1){    // log-map at origin: (2/sc)*artanh(sc*|y|)/|y|
        float x = sc * nrm;
        sca = (nrm > 1e-30f) ? (logf((1.f + x)/(1.f - x)) / (sc * nrm)) : 2.f;
      } else {        // l2norm
        sca = 1.f / fmaxf(nrm, 1e-12f);
      }
      #pragma unroll
      for (int i = 0; i < 8; ++i){ c[i].x*=sca; c[i].y*=sca; c[i].z*=sca; c[i].w*=sca; }
    }
    // ---- pack to bf16 frags + MFMA (W a-frags from LDS) ----
    f32x4 acc[8];
    #pragma unroll
    for (int ct = 0; ct < 8; ++ct){ f32x4 z = {0.f,0.f,0.f,0.f}; acc[ct] = z; }
    #pragma unroll
    for (int ks = 0; ks < 4; ++ks){
      u32x4 bq;
      bq.x = f2bf2(c[2*ks].x,   c[2*ks].y);
      bq.y = f2bf2(c[2*ks].z,   c[2*ks].w);
      bq.z = f2bf2(c[2*ks+1].x, c[2*ks+1].y);
      bq.w = f2bf2(c[2*ks+1].z, c[2*ks+1].w);
      short8 bf = __builtin_bit_cast(short8, bq);
      #pragma unroll
      for (int ct = 0; ct < 8; ++ct){
        short8 wf = *(const short8*)&Wlds[((ct*4 + ks)*64 + lane)*4];
        acc[ct] = __builtin_amdgcn_mfma_f32_16x16x32_bf16(wf, bf, acc[ct], 0, 0, 0);
      }
    }
    // ---- epilogue: bias (+ spherical l2norm), bf16 pack, store ----
    #pragma unroll
    for (int ct = 0; ct < 8; ++ct){
      acc[ct].x += bv[ct].x; acc[ct].y += bv[ct].y;
      acc[ct].z += bv[ct].z; acc[ct].w += bv[ct].w;
    }
    if (m == 2){
      float p = 0.f;
      #pragma unroll
      for (int ct = 0; ct < 8; ++ct)
        p += acc[ct].x*acc[ct].x + acc[ct].y*acc[ct].y + acc[ct].z*acc[ct].z + acc[ct].w*acc[ct].w;
      p += __shfl_xor(p, 16, 64);
      p += __shfl_xor(p, 32, 64);
      float inv = 1.f / fmaxf(sqrtf(p), 1e-12f);
      #pragma unroll
      for (int ct = 0; ct < 8; ++ct){ acc[ct].x*=inv; acc[ct].y*=inv; acc[ct].z*=inv; acc[ct].w*=inv; }
    }
    u32* hp = H + (size_t)(g*16 + rr)*64 + quad*2;   // channel = ct*16 + quad*4 + reg
    #pragma unroll
    for (int ct = 0; ct < 8; ++ct){
      uint2 pk;
      pk.x = f2bf2(acc[ct].x, acc[ct].y);
      pk.y = f2bf2(acc[ct].z, acc[ct].w);
      *(uint2*)(hp + ct*8) = pk;
    }
    if (g2 < 3125){
      #pragma unroll
      for (int i = 0; i < 8; ++i) c[i] = cn[i];
    }
  }
}

// ------- mean-aggregate + post-transform; one wave per node, 16 lanes/edge --------
// lane-group lg=lane>>4 owns edge slot lg of each 4-edge pass; lane owns 16 B (8 bf16).
struct AggArgs {
  const u32* H;
  float* O;
  const int* row_start;
  const int* esrc;
  const float* curv;
};

__device__ __forceinline__ void acc8(float* a, uint4 q){
  a[0]+=blo(q.x); a[1]+=bhi(q.x); a[2]+=blo(q.y); a[3]+=bhi(q.y);
  a[4]+=blo(q.z); a[5]+=bhi(q.z); a[6]+=blo(q.w); a[7]+=bhi(q.w);
}
__device__ __forceinline__ void facc8(float* a, uint4 q, float w){
  a[0]+=w*blo(q.x); a[1]+=w*bhi(q.x); a[2]+=w*blo(q.y); a[3]+=w*bhi(q.y);
  a[4]+=w*blo(q.z); a[5]+=w*bhi(q.z); a[6]+=w*blo(q.w); a[7]+=w*bhi(q.w);
}

__global__ __launch_bounds__(256) void k_agg(AggArgs aa){
  const int tid = threadIdx.x;
  const int lane = tid & 63;
  const int lg = lane >> 4, hl = lane & 15;
  const int node = blockIdx.x*4 + (tid >> 6);
  if (node >= NN) return;
  const int e0 = aa.row_start[node], e1 = aa.row_start[node+1];
  const int* __restrict__ esrc = aa.esrc;
  const u32* __restrict__ h0 = aa.H;
  const u32* __restrict__ h1 = aa.H + (size_t)NN*64;
  const u32* __restrict__ h2 = aa.H + (size_t)2*NN*64;
  const int fo = hl*4;              // u32 offset: 16 B per lane within the 256-B row

  float a0[8] = {0,0,0,0,0,0,0,0};
  float a1[8] = {0,0,0,0,0,0,0,0};
  float a2[8] = {0,0,0,0,0,0,0,0};

  for (int base = e0; base < e1; base += 64){
    int nn = e1 - base; if (nn > 64) nn = 64;
    int sv = esrc[min(base + lane, e1 - 1)];   // 64 edge indices, one coalesced load
    int np = nn >> 2;
    int p = 0;
    for (; p + 2 <= np; p += 2){               // 8 edges, 6 dwordx4 gathers in flight
      int sA = __shfl(sv, 4*p     + lg, 64);
      int sB = __shfl(sv, 4*p + 4 + lg, 64);
      size_t oA = (size_t)sA*64 + fo;
      size_t oB = (size_t)sB*64 + fo;
      uint4 qA0 = *(const uint4*)(h0 + oA);
      uint4 qA1 = *(const uint4*)(h1 + oA);
      uint4 qA2 = *(const uint4*)(h2 + oA);
      uint4 qB0 = *(const uint4*)(h0 + oB);
      uint4 qB1 = *(const uint4*)(h1 + oB);
      uint4 qB2 = *(const uint4*)(h2 + oB);
      acc8(a0, qA0); acc8(a1, qA1); acc8(a2, qA2);
      acc8(a0, qB0); acc8(a1, qB1); acc8(a2, qB2);
    }
    for (; p < np; ++p){
      int sA = __shfl(sv, 4*p + lg, 64);
      size_t oA = (size_t)sA*64 + fo;
      uint4 q0 = *(const uint4*)(h0 + oA);
      uint4 q1 = *(const uint4*)(h1 + oA);
      uint4 q2 = *(const uint4*)(h2 + oA);
      acc8(a0, q0); acc8(a1, q1); acc8(a2, q2);
    }
    int rem = nn & 3;
    if (rem){                                  // tail: mask-weighted, once per chunk
      int idx = 4*np + lg;
      float w = (idx < nn) ? 1.f : 0.f;
      int sA = __shfl(sv, min(idx, nn - 1), 64);
      size_t oA = (size_t)sA*64 + fo;
      uint4 q0 = *(const uint4*)(h0 + oA);
      uint4 q1 = *(const uint4*)(h1 + oA);
      uint4 q2 = *(const uint4*)(h2 + oA);
      facc8(a0, q0, w); facc8(a1, q1, w); facc8(a2, q2, w);
    }
  }

  // combine the 4 lane-group edge partitions (butterfly over lane bits 4,5)
  #pragma unroll
  for (int j = 0; j < 8; ++j){
    a0[j] += __shfl_xor(a0[j], 16, 64); a0[j] += __shfl_xor(a0[j], 32, 64);
    a1[j] += __shfl_xor(a1[j], 16, 64); a1[j] += __shfl_xor(a1[j], 32, 64);
    a2[j] += __shfl_xor(a2[j], 16, 64); a2[j] += __shfl_xor(a2[j], 32, 64);
  }
  float inv = 1.f / (float)max(e1 - e0, 1);
  #pragma unroll
  for (int j = 0; j < 8; ++j){ a0[j]*=inv; a1[j]*=inv; a2[j]*=inv; }

  // row-norm reductions over the 16 feature-lanes (bits 0..3)
  float p1 = 0.f, p2 = 0.f;
  #pragma unroll
  for (int j = 0; j < 8; ++j){ p1 += a1[j]*a1[j]; p2 += a2[j]*a2[j]; }
  #pragma unroll
  for (int off = 1; off < 16; off <<= 1){
    p1 += __shfl_xor(p1, off, 64);
    p2 += __shfl_xor(p2, off, 64);
  }
  float n1 = sqrtf(p1);
  float scv = sqrtf(*aa.curv);
  float x = scv * n1;
  float s1 = (n1 > 1e-30f) ? (tanhf(0.5f*x) / x) : 0.5f;   // exp-map at origin
  float s2 = 1.f / fmaxf(sqrtf(p2), 1e-12f);               // l2norm

  // contiguous stores: lane-groups 0/1/2 write manifold 0/1/2 (48 lanes x 32 B)
  float* op = aa.O + (size_t)node*384 + lg*128 + hl*8;
  if (lg == 0){
    *(float4*)(op)     = make_float4(a0[0]>0.f?a0[0]:0.2f*a0[0], a0[1]>0.f?a0[1]:0.2f*a0[1],
                                     a0[2]>0.f?a0[2]:0.2f*a0[2], a0[3]>0.f?a0[3]:0.2f*a0[3]);
    *(float4*)(op + 4) = make_float4(a0[4]>0.f?a0[4]:0.2f*a0[4], a0[5]>0.f?a0[5]:0.2f*a0[5],
                                     a0[6]>0.f?a0[6]:0.2f*a0[6], a0[7]>0.f?a0[7]:0.2f*a0[7]);
  } else if (lg == 1){
    *(float4*)(op)     = make_float4(a1[0]*s1, a1[1]*s1, a1[2]*s1, a1[3]*s1);
    *(float4*)(op + 4) = make_float4(a1[4]*s1, a1[5]*s1, a1[6]*s1, a1[7]*s1);
  } else if (lg == 2){
    *(float4*)(op)     = make_float4(a2[0]*s2, a2[1]*s2, a2[2]*s2, a2[3]*s2);
    *(float4*)(op + 4) = make_float4(a2[4]*s2, a2[5]*s2, a2[6]*s2, a2[7]*s2);
  }
}

extern "C" void kernel_launch(void* const* d_in, const int* in_sizes, int n_in,
                              void* d_out, int out_size, void* d_ws, size_t ws_size,
                              hipStream_t stream){
  (void)in_sizes; (void)n_in; (void)out_size; (void)ws_size;
  const int*   src    = (const int*)  d_in[0];
  const int*   dst    = (const int*)  d_in[1];
  const float* e_emb  = (const float*)d_in[2];
  const float* b_emb  = (const float*)d_in[3];
  const float* s_emb  = (const float*)d_in[4];
  const float* e_W    = (const float*)d_in[5];
  const float* e_b    = (const float*)d_in[6];
  const float* b_W    = (const float*)d_in[7];
  const float* b_b    = (const float*)d_in[8];
  const float* s_W    = (const float*)d_in[9];
  const float* s_b    = (const float*)d_in[10];
  const float* b_curv = (const float*)d_in[11];
  float* out = (float*)d_out;

  char* ws = (char*)d_ws;
  size_t off = 0;
  auto alloc = [&](size_t bytes) -> void* {
    void* p = (void*)(ws + off);
    off += (bytes + 255) & ~(size_t)255;
    return p;
  };
  int* cnt       = (int*)alloc((size_t)NN*4);
  int* row_start = (int*)alloc((size_t)(NN+1)*4);
  int* cursor    = (int*)alloc((size_t)NN*4);
  int* esrc      = (int*)alloc((size_t)NE*4);
  u32* h         = (u32*)alloc((size_t)3*NN*64*4);
  u32* wf        = (u32*)alloc((size_t)6*2048*16);   // frag-packed bf16 weights
  int* btot      = (int*)alloc(64*4);
  int* bbase     = (int*)alloc(64*4);

  (void)hipMemsetAsync(cnt, 0, (size_t)NN*4, stream);

  PrepArgs pp;
  pp.W[0] = e_W;          pp.W[1] = b_W;          pp.W[2] = s_W;
  pp.W[3] = e_W + 16384;  pp.W[4] = b_W + 16384;  pp.W[5] = s_W + 16384;
  pp.out = wf;
  k_prep   <<<48, 256, 0, stream>>>(pp);

  k_hist   <<<NE/256, 256, 0, stream>>>(dst, cnt);
  k_scan1  <<<49, 1024, 0, stream>>>(cnt, row_start, btot);
  k_scan2  <<<1, 64, 0, stream>>>(btot, bbase, row_start);
  k_scan3  <<<49, 1024, 0, stream>>>(row_start, bbase, cursor);
  k_scatter<<<NE/256, 256, 0, stream>>>(src, dst, cursor, esrc);

  GemmArgs g;
  g.H = h; g.curv = b_curv;
  AggArgs a;
  a.H = h; a.O = out; a.row_start = row_start; a.esrc = esrc; a.curv = b_curv;

  dim3 ggrid(157, 3);          // 628 waves per manifold, ~5 groups/wave
  int agrid = (NN + 3)/4;

  // ----- layer 0 -----
  g.astride = DD;
  g.A[0]=e_emb; g.A[1]=b_emb; g.A[2]=s_emb;
  g.Bias[0]=e_b; g.Bias[1]=b_b; g.Bias[2]=s_b;
  g.Wf = wf;
  k_gemm<<<ggrid, 256, 0, stream>>>(g);
  k_agg <<<agrid, 256, 0, stream>>>(a);

  // ----- layer 1 (reads d_out strided, overwrites d_out) -----
  g.astride = 3*DD;
  g.A[0]=out; g.A[1]=out+DD; g.A[2]=out+2*DD;
  g.Bias[0]=e_b+DD; g.Bias[1]=b_b+DD; g.Bias[2]=s_b+DD;
  g.Wf = wf + 3*8192;
  k_gemm<<<ggrid, 256, 0, stream>>>(g);
  k_agg <<<agrid, 256, 0, stream>>>(a);
}